// Round 5
// baseline (269.040 us; speedup 1.0000x reference)
//
#include <hip/hip_runtime.h>
#include <hip/hip_bf16.h>

#define N_NODES 50000
#define N_EDGES 600000
#define DIM 128
#define CAP 64          // bucket capacity; deg ~ Poisson(12), P(>64) ~ 1e-30, guarded anyway

typedef short bf16x8 __attribute__((ext_vector_type(8)));
typedef float f32x4 __attribute__((ext_vector_type(4)));

__device__ __forceinline__ ushort f2b(float f) {
    __hip_bfloat16 h = __float2bfloat16(f);
    return *reinterpret_cast<ushort*>(&h);
}
__device__ __forceinline__ float b2f_lo(unsigned u) { return __uint_as_float(u << 16); }
__device__ __forceinline__ float b2f_hi(unsigned u) { return __uint_as_float(u & 0xffff0000u); }

static constexpr size_t alignup(size_t x) { return (x + 255) & ~size_t(255); }
static constexpr size_t OFF_FLAG = 0;
static constexpr size_t OFF_CNT  = 256;
static constexpr size_t OFF_COL  = alignup(OFF_CNT + sizeof(unsigned) * N_NODES);
static constexpr size_t OFF_XBF  = alignup(OFF_COL + sizeof(int) * (size_t)N_NODES * CAP);
static constexpr size_t OFF_H1   = alignup(OFF_XBF + sizeof(ushort) * N_NODES * DIM);
static constexpr size_t OFF_H2   = alignup(OFF_H1 + sizeof(ushort) * N_NODES * DIM);
static constexpr size_t OFF_WL0  = alignup(OFF_H2 + sizeof(ushort) * N_NODES * DIM);
static constexpr size_t OFF_WR0  = alignup(OFF_WL0 + sizeof(ushort) * DIM * DIM);
static constexpr size_t OFF_WL1  = alignup(OFF_WR0 + sizeof(ushort) * DIM * DIM);
static constexpr size_t OFF_WR1  = alignup(OFF_WL1 + sizeof(ushort) * DIM * DIM);

// ---- init: zero cnt; block 0 also detects edge dtype (int64 => odd 32b words all zero) ----
__global__ __launch_bounds__(256) void init_k(const int* __restrict__ ei,
                                              unsigned* __restrict__ flag,
                                              unsigned* __restrict__ cnt) {
    const int i = blockIdx.x * 256 + threadIdx.x;
    if (i < N_NODES) cnt[i] = 0u;
    if (blockIdx.x == 0) {
        __shared__ unsigned any;
        if (threadIdx.x == 0) any = 0u;
        __syncthreads();
        unsigned v = 0;
#pragma unroll
        for (int j = 0; j < 4; ++j)
            v |= (unsigned)ei[2 * (threadIdx.x * 4 + j) + 1];
        if (v) atomicOr(&any, 1u);
        __syncthreads();
        if (threadIdx.x == 0) *flag = any;   // !=0 -> int32 layout, ==0 -> int64 layout
    }
}

// ---- bucketed CSR fill: col[dst*CAP + pos], cnt[dst] ends as degree. 4 edges/thread ----
__global__ void fillcsr_k(const int* __restrict__ ei, const unsigned* __restrict__ flag,
                          unsigned* __restrict__ cnt, int* __restrict__ col) {
    int e0 = (blockIdx.x * 256 + threadIdx.x) * 4;
    if (e0 >= N_EDGES) return;
    int s[4], d[4];
    if (*flag) {
        uint4 sv = *reinterpret_cast<const uint4*>(&ei[e0]);
        uint4 dv = *reinterpret_cast<const uint4*>(&ei[N_EDGES + e0]);
        s[0] = sv.x; s[1] = sv.y; s[2] = sv.z; s[3] = sv.w;
        d[0] = dv.x; d[1] = dv.y; d[2] = dv.z; d[3] = dv.w;
    } else {
        uint4 sa = *reinterpret_cast<const uint4*>(&ei[2 * e0]);
        uint4 sb = *reinterpret_cast<const uint4*>(&ei[2 * e0 + 4]);
        uint4 da = *reinterpret_cast<const uint4*>(&ei[2 * (N_EDGES + e0)]);
        uint4 db = *reinterpret_cast<const uint4*>(&ei[2 * (N_EDGES + e0) + 4]);
        s[0] = sa.x; s[1] = sa.z; s[2] = sb.x; s[3] = sb.z;
        d[0] = da.x; d[1] = da.z; d[2] = db.x; d[3] = db.z;
    }
#pragma unroll
    for (int i = 0; i < 4; ++i) {
        unsigned pos = atomicAdd(&cnt[d[i]], 1u);
        if (pos < CAP) col[(size_t)d[i] * CAP + pos] = s[i];
    }
}

// ---- f32 -> bf16 converters ----
__global__ __launch_bounds__(256) void f2b_k(const float* __restrict__ src,
                                             ushort* __restrict__ dst, int n4) {
    int i = blockIdx.x * 256 + threadIdx.x;
    if (i >= n4) return;
    float4 v = reinterpret_cast<const float4*>(src)[i];
    ushort4 o;
    o.x = f2b(v.x); o.y = f2b(v.y); o.z = f2b(v.z); o.w = f2b(v.w);
    reinterpret_cast<ushort4*>(dst)[i] = o;
}

__global__ __launch_bounds__(256) void wconv_k(const float* __restrict__ a, const float* __restrict__ b,
                                               const float* __restrict__ c, const float* __restrict__ d,
                                               ushort* __restrict__ oa, ushort* __restrict__ ob,
                                               ushort* __restrict__ oc, ushort* __restrict__ od) {
    const int w = blockIdx.y;
    const float* src = (w == 0) ? a : (w == 1) ? b : (w == 2) ? c : d;
    ushort* dst      = (w == 0) ? oa : (w == 1) ? ob : (w == 2) ? oc : od;
    int i = blockIdx.x * 256 + threadIdx.x;          // DIM*DIM/4 = 4096 threads
    float4 v = reinterpret_cast<const float4*>(src)[i];
    ushort4 o;
    o.x = f2b(v.x); o.y = f2b(v.y); o.z = f2b(v.z); o.w = f2b(v.w);
    reinterpret_cast<ushort4*>(dst)[i] = o;
}

// ---- fused layer: mean-aggregate (into LDS) + [relu](agg@Wl^T + b + root@Wr^T) via MFMA ----
// 64 nodes/block, 256 threads. LDS: Ws[128][136] (W tile, 272B stride) + Ag[64][136] (agg bf16).
// Phases: stage Wl & issue root loads -> gather/agg -> bar -> MFMA(Ag x Wl) -> bar ->
//         stage Wr -> bar -> MFMA(root x Wr) -> epilogue.
template <bool RELU>
__global__ __launch_bounds__(256) void layer_fused_k(const ushort* __restrict__ hin,
                                                     const unsigned* __restrict__ cnt,
                                                     const int* __restrict__ col,
                                                     const ushort* __restrict__ Wl,
                                                     const ushort* __restrict__ Wr,
                                                     const float*  __restrict__ bias,
                                                     ushort* __restrict__ hout) {
    __shared__ ushort Ws[128 * 136];                 // 34816 B
    __shared__ ushort Ag[64 * 136];                  // 17408 B
    const int t    = threadIdx.x;
    const int wave = t >> 6;
    const int l    = t & 63;
    const int l16  = l & 15;
    const int lk   = (l >> 4) * 8;
    const int node = blockIdx.x * 64 + wave * 16 + l16;
    const bool valid = node < N_NODES;

    const int wrow = t >> 1;
    const int wc0  = (t & 1) * 64;

    const bf16x8 zfrag = (bf16x8){0, 0, 0, 0, 0, 0, 0, 0};

    // issue root-feature loads early (independent of everything below)
    bf16x8 rootf[4];
#pragma unroll
    for (int ks = 0; ks < 4; ++ks)
        rootf[ks] = valid
            ? *reinterpret_cast<const bf16x8*>(&hin[(size_t)node * DIM + ks * 32 + lk])
            : zfrag;

    {   // stage Wl -> Ws (coalesced, 128B/thread)
        const uint4* src = reinterpret_cast<const uint4*>(&Wl[(size_t)wrow * DIM + wc0]);
        uint4* dst = reinterpret_cast<uint4*>(&Ws[wrow * 136 + wc0]);
#pragma unroll
        for (int i = 0; i < 8; ++i) dst[i] = src[i];
    }

    // gather/mean-aggregate 64 nodes in 4 chunks of 16 (16 lanes/node, 8 feats/lane)
    const int g = t >> 4, lane = t & 15;
#pragma unroll
    for (int nch = 0; nch < 4; ++nch) {
        const int an = blockIdx.x * 64 + nch * 16 + g;
        uint4 o = {0u, 0u, 0u, 0u};
        if (an < N_NODES) {
            unsigned deg = cnt[an];
            if (deg > CAP) deg = CAP;
            float acc[8];
#pragma unroll
            for (int i = 0; i < 8; ++i) acc[i] = 0.f;
            const int* cp = &col[(size_t)an * CAP];
            for (unsigned e = 0; e < deg; ++e) {
                int s = cp[e];
                uint4 v = *reinterpret_cast<const uint4*>(&hin[(size_t)s * DIM + lane * 8]);
                acc[0] += b2f_lo(v.x); acc[1] += b2f_hi(v.x);
                acc[2] += b2f_lo(v.y); acc[3] += b2f_hi(v.y);
                acc[4] += b2f_lo(v.z); acc[5] += b2f_hi(v.z);
                acc[6] += b2f_lo(v.w); acc[7] += b2f_hi(v.w);
            }
            const float inv = 1.0f / fmaxf((float)deg, 1.0f);
            o.x = (unsigned)f2b(acc[0] * inv) | ((unsigned)f2b(acc[1] * inv) << 16);
            o.y = (unsigned)f2b(acc[2] * inv) | ((unsigned)f2b(acc[3] * inv) << 16);
            o.z = (unsigned)f2b(acc[4] * inv) | ((unsigned)f2b(acc[5] * inv) << 16);
            o.w = (unsigned)f2b(acc[6] * inv) | ((unsigned)f2b(acc[7] * inv) << 16);
        }
        *reinterpret_cast<uint4*>(&Ag[(nch * 16 + g) * 136 + lane * 8]) = o;
    }

    __syncthreads();   // Ws(Wl) + Ag ready

    f32x4 acc8[8];
#pragma unroll
    for (int i = 0; i < 8; ++i) acc8[i] = (f32x4){0.f, 0.f, 0.f, 0.f};

    const int nl = wave * 16 + l16;
#pragma unroll
    for (int ks = 0; ks < 4; ++ks) {
        const int kb = ks * 32;
        const bf16x8 bfrag = *reinterpret_cast<const bf16x8*>(&Ag[nl * 136 + kb + lk]);
#pragma unroll
        for (int ot = 0; ot < 8; ++ot) {
            const bf16x8 afrag = *reinterpret_cast<const bf16x8*>(
                &Ws[(ot * 16 + l16) * 136 + kb + lk]);
            acc8[ot] = __builtin_amdgcn_mfma_f32_16x16x32_bf16(afrag, bfrag, acc8[ot], 0, 0, 0);
        }
    }

    __syncthreads();   // done reading Ws(Wl)
    {   // stage Wr -> Ws
        const uint4* src = reinterpret_cast<const uint4*>(&Wr[(size_t)wrow * DIM + wc0]);
        uint4* dst = reinterpret_cast<uint4*>(&Ws[wrow * 136 + wc0]);
#pragma unroll
        for (int i = 0; i < 8; ++i) dst[i] = src[i];
    }
    __syncthreads();   // Ws(Wr) ready

#pragma unroll
    for (int ks = 0; ks < 4; ++ks) {
        const int kb = ks * 32;
#pragma unroll
        for (int ot = 0; ot < 8; ++ot) {
            const bf16x8 afrag = *reinterpret_cast<const bf16x8*>(
                &Ws[(ot * 16 + l16) * 136 + kb + lk]);
            acc8[ot] = __builtin_amdgcn_mfma_f32_16x16x32_bf16(afrag, rootf[ks], acc8[ot], 0, 0, 0);
        }
    }

    if (!valid) return;
    const int orow = (l >> 4) * 4;
#pragma unroll
    for (int ot = 0; ot < 8; ++ot) {
        const float4 b4 = *reinterpret_cast<const float4*>(&bias[ot * 16 + orow]);
        float r0 = acc8[ot][0] + b4.x;
        float r1 = acc8[ot][1] + b4.y;
        float r2 = acc8[ot][2] + b4.z;
        float r3 = acc8[ot][3] + b4.w;
        if (RELU) {
            r0 = fmaxf(r0, 0.f); r1 = fmaxf(r1, 0.f);
            r2 = fmaxf(r2, 0.f); r3 = fmaxf(r3, 0.f);
        }
        ushort4 s;
        s.x = f2b(r0); s.y = f2b(r1); s.z = f2b(r2); s.w = f2b(r3);
        *reinterpret_cast<ushort4*>(&hout[(size_t)node * DIM + ot * 16 + orow]) = s;
    }
}

// ---- final layer fused: mean-aggregate h2 + 2-dim linear, f32 throughout ----
__global__ __launch_bounds__(256) void out2_fused_k(const ushort* __restrict__ h,
                                                    const unsigned* __restrict__ cnt,
                                                    const int* __restrict__ col,
                                                    const float* __restrict__ Wl,
                                                    const float* __restrict__ Wr,
                                                    const float* __restrict__ bias,
                                                    float* __restrict__ out) {
    __shared__ float wl[256], wr[256];                // [o*128 + k]
    const int t = threadIdx.x;
    wl[t] = Wl[t];
    wr[t] = Wr[t];
    __syncthreads();
    const int g = t >> 4, lane = t & 15;
    const int node = blockIdx.x * 16 + g;
    if (node >= N_NODES) return;
    unsigned deg = cnt[node];
    if (deg > CAP) deg = CAP;
    float acc[8];
#pragma unroll
    for (int i = 0; i < 8; ++i) acc[i] = 0.f;
    const int* cp = &col[(size_t)node * CAP];
    for (unsigned e = 0; e < deg; ++e) {
        int s = cp[e];
        uint4 v = *reinterpret_cast<const uint4*>(&h[(size_t)s * DIM + lane * 8]);
        acc[0] += b2f_lo(v.x); acc[1] += b2f_hi(v.x);
        acc[2] += b2f_lo(v.y); acc[3] += b2f_hi(v.y);
        acc[4] += b2f_lo(v.z); acc[5] += b2f_hi(v.z);
        acc[6] += b2f_lo(v.w); acc[7] += b2f_hi(v.w);
    }
    const float inv = 1.0f / fmaxf((float)deg, 1.0f);
    const uint4 rv = *reinterpret_cast<const uint4*>(&h[(size_t)node * DIM + lane * 8]);
    float root[8];
    root[0] = b2f_lo(rv.x); root[1] = b2f_hi(rv.x);
    root[2] = b2f_lo(rv.y); root[3] = b2f_hi(rv.y);
    root[4] = b2f_lo(rv.z); root[5] = b2f_hi(rv.z);
    root[6] = b2f_lo(rv.w); root[7] = b2f_hi(rv.w);
    const int kb = lane * 8;
    float p0 = 0.f, p1 = 0.f;
#pragma unroll
    for (int j = 0; j < 8; ++j) {
        const float av = acc[j] * inv;
        p0 += av * wl[kb + j] + root[j] * wr[kb + j];
        p1 += av * wl[128 + kb + j] + root[j] * wr[128 + kb + j];
    }
#pragma unroll
    for (int m = 1; m < 16; m <<= 1) {
        p0 += __shfl_xor(p0, m);
        p1 += __shfl_xor(p1, m);
    }
    if (lane == 0) {
        out[(size_t)node * 2 + 0] = p0 + bias[0];
        out[(size_t)node * 2 + 1] = p1 + bias[1];
    }
}

extern "C" void kernel_launch(void* const* d_in, const int* in_sizes, int n_in,
                              void* d_out, int out_size, void* d_ws, size_t ws_size,
                              hipStream_t stream) {
    const float* x   = (const float*)d_in[0];
    const int*   ei  = (const int*)d_in[1];
    const float* Wl0 = (const float*)d_in[2];
    const float* Wr0 = (const float*)d_in[3];
    const float* b0  = (const float*)d_in[4];
    const float* Wl1 = (const float*)d_in[5];
    const float* Wr1 = (const float*)d_in[6];
    const float* b1  = (const float*)d_in[7];
    const float* Wl2 = (const float*)d_in[8];
    const float* Wr2 = (const float*)d_in[9];
    const float* b2  = (const float*)d_in[10];

    char* ws = (char*)d_ws;
    unsigned* flag = (unsigned*)(ws + OFF_FLAG);
    unsigned* cnt  = (unsigned*)(ws + OFF_CNT);
    int*      col  = (int*)(ws + OFF_COL);
    ushort*   xbf  = (ushort*)(ws + OFF_XBF);
    ushort*   h1   = (ushort*)(ws + OFF_H1);
    ushort*   h2   = (ushort*)(ws + OFF_H2);
    ushort*   wl0b = (ushort*)(ws + OFF_WL0);
    ushort*   wr0b = (ushort*)(ws + OFF_WR0);
    ushort*   wl1b = (ushort*)(ws + OFF_WL1);
    ushort*   wr1b = (ushort*)(ws + OFF_WR1);
    float*    out  = (float*)d_out;

    init_k<<<(N_NODES + 255) / 256, 256, 0, stream>>>(ei, flag, cnt);
    fillcsr_k<<<(N_EDGES / 4 + 255) / 256, 256, 0, stream>>>(ei, flag, cnt, col);
    f2b_k<<<(N_NODES * DIM / 4 + 255) / 256, 256, 0, stream>>>(x, xbf, N_NODES * DIM / 4);
    wconv_k<<<dim3(DIM * DIM / 4 / 256, 4), 256, 0, stream>>>(Wl0, Wr0, Wl1, Wr1,
                                                              wl0b, wr0b, wl1b, wr1b);

    layer_fused_k<true><<<(N_NODES + 63) / 64, 256, 0, stream>>>(xbf, cnt, col, wl0b, wr0b, b0, h1);
    layer_fused_k<true><<<(N_NODES + 63) / 64, 256, 0, stream>>>(h1, cnt, col, wl1b, wr1b, b1, h2);
    out2_fused_k<<<(N_NODES + 15) / 16, 256, 0, stream>>>(h2, cnt, col, Wl2, Wr2, b2, out);
}

// Round 6
// 152.833 us; speedup vs baseline: 1.7604x; 1.7604x over previous
//
#include <hip/hip_runtime.h>
#include <hip/hip_bf16.h>

#define N_NODES 50000
#define N_EDGES 600000
#define DIM 128
#define CAP 64          // bucket capacity; deg ~ Poisson(12), max over 50K nodes ~ 38, guarded anyway

typedef short bf16x8 __attribute__((ext_vector_type(8)));
typedef float f32x4 __attribute__((ext_vector_type(4)));

__device__ __forceinline__ ushort f2b(float f) {
    __hip_bfloat16 h = __float2bfloat16(f);
    return *reinterpret_cast<ushort*>(&h);
}
__device__ __forceinline__ float b2f_lo(unsigned u) { return __uint_as_float(u << 16); }
__device__ __forceinline__ float b2f_hi(unsigned u) { return __uint_as_float(u & 0xffff0000u); }

static constexpr size_t alignup(size_t x) { return (x + 255) & ~size_t(255); }
static constexpr size_t OFF_FLAG = 0;
static constexpr size_t OFF_CNT  = 256;
static constexpr size_t OFF_COL  = alignup(OFF_CNT + sizeof(unsigned) * N_NODES);
static constexpr size_t OFF_XBF  = alignup(OFF_COL + sizeof(int) * (size_t)N_NODES * CAP);
static constexpr size_t OFF_AGG  = alignup(OFF_XBF + sizeof(ushort) * N_NODES * DIM);
static constexpr size_t OFF_H1   = alignup(OFF_AGG + sizeof(ushort) * N_NODES * DIM);
static constexpr size_t OFF_H2   = alignup(OFF_H1 + sizeof(ushort) * N_NODES * DIM);
static constexpr size_t OFF_WL0  = alignup(OFF_H2 + sizeof(ushort) * N_NODES * DIM);
static constexpr size_t OFF_WR0  = alignup(OFF_WL0 + sizeof(ushort) * DIM * DIM);
static constexpr size_t OFF_WL1  = alignup(OFF_WR0 + sizeof(ushort) * DIM * DIM);
static constexpr size_t OFF_WR1  = alignup(OFF_WL1 + sizeof(ushort) * DIM * DIM);

// ---- prep: zero cnt + detect edge dtype + x->bf16 + 4x W->bf16, one dispatch ----
// grid: 6250 blocks for f2b (6.4M floats / 4 per thread) + 64 blocks for wconv
__global__ __launch_bounds__(256) void prep_k(const int* __restrict__ ei,
                                              const float* __restrict__ x,
                                              const float* __restrict__ wa, const float* __restrict__ wb,
                                              const float* __restrict__ wc, const float* __restrict__ wd,
                                              unsigned* __restrict__ flag,
                                              unsigned* __restrict__ cnt,
                                              ushort* __restrict__ xbf,
                                              ushort* __restrict__ oa, ushort* __restrict__ ob,
                                              ushort* __restrict__ oc, ushort* __restrict__ od) {
    const int bid = blockIdx.x, t = threadIdx.x;
    if (bid < 6250) {
        const int i = bid * 256 + t;                 // f2b: 4 floats/thread
        float4 v = reinterpret_cast<const float4*>(x)[i];
        ushort4 o;
        o.x = f2b(v.x); o.y = f2b(v.y); o.z = f2b(v.z); o.w = f2b(v.w);
        reinterpret_cast<ushort4*>(xbf)[i] = o;
        if (i < N_NODES) cnt[i] = 0u;
        if (bid == 0) {
            __shared__ unsigned any;
            if (t == 0) any = 0u;
            __syncthreads();
            unsigned hv = 0;
#pragma unroll
            for (int j = 0; j < 4; ++j) hv |= (unsigned)ei[2 * (t * 4 + j) + 1];
            if (hv) atomicOr(&any, 1u);
            __syncthreads();
            if (t == 0) *flag = any;                 // !=0 -> int32 layout, ==0 -> int64
        }
    } else {
        const int wb_i = bid - 6250;                 // 64 blocks: 4 mats x 16 blocks
        const int w = wb_i >> 4;
        const float* src = (w == 0) ? wa : (w == 1) ? wb : (w == 2) ? wc : wd;
        ushort* dst      = (w == 0) ? oa : (w == 1) ? ob : (w == 2) ? oc : od;
        const int i = (wb_i & 15) * 256 + t;         // 4096 float4 units per matrix
        float4 v = reinterpret_cast<const float4*>(src)[i];
        ushort4 o;
        o.x = f2b(v.x); o.y = f2b(v.y); o.z = f2b(v.z); o.w = f2b(v.w);
        reinterpret_cast<ushort4*>(dst)[i] = o;
    }
}

// ---- bucketed CSR fill: col[dst*CAP + pos], cnt[dst] ends as degree. 4 edges/thread ----
__global__ void fillcsr_k(const int* __restrict__ ei, const unsigned* __restrict__ flag,
                          unsigned* __restrict__ cnt, int* __restrict__ col) {
    int e0 = (blockIdx.x * 256 + threadIdx.x) * 4;
    if (e0 >= N_EDGES) return;
    int s[4], d[4];
    if (*flag) {
        uint4 sv = *reinterpret_cast<const uint4*>(&ei[e0]);
        uint4 dv = *reinterpret_cast<const uint4*>(&ei[N_EDGES + e0]);
        s[0] = sv.x; s[1] = sv.y; s[2] = sv.z; s[3] = sv.w;
        d[0] = dv.x; d[1] = dv.y; d[2] = dv.z; d[3] = dv.w;
    } else {
        uint4 sa = *reinterpret_cast<const uint4*>(&ei[2 * e0]);
        uint4 sb = *reinterpret_cast<const uint4*>(&ei[2 * e0 + 4]);
        uint4 da = *reinterpret_cast<const uint4*>(&ei[2 * (N_EDGES + e0)]);
        uint4 db = *reinterpret_cast<const uint4*>(&ei[2 * (N_EDGES + e0) + 4]);
        s[0] = sa.x; s[1] = sa.z; s[2] = sb.x; s[3] = sb.z;
        d[0] = da.x; d[1] = da.z; d[2] = db.x; d[3] = db.z;
    }
#pragma unroll
    for (int i = 0; i < 4; ++i) {
        unsigned pos = atomicAdd(&cnt[d[i]], 1u);
        if (pos < CAP) col[(size_t)d[i] * CAP + pos] = s[i];
    }
}

// ---- mean-aggregate (bf16 in, f32 accum, bf16 out): 16 nodes/block, 16 lanes/node ----
// 4-way unrolled gather: 4 independent uint4 loads in flight per iteration.
__global__ __launch_bounds__(256) void agg_k(const ushort* __restrict__ h,
                                             const unsigned* __restrict__ cnt,
                                             const int* __restrict__ col,
                                             ushort* __restrict__ aggm) {
    const int g = threadIdx.x >> 4, lane = threadIdx.x & 15;
    const int node = blockIdx.x * 16 + g;
    if (node >= N_NODES) return;
    unsigned deg = cnt[node];
    if (deg > CAP) deg = CAP;
    const int* cp = &col[(size_t)node * CAP];
    float acc[8];
#pragma unroll
    for (int i = 0; i < 8; ++i) acc[i] = 0.f;
    const int co = lane * 8;
    unsigned e = 0;
    for (; e + 4 <= deg; e += 4) {
        const int s0 = cp[e], s1 = cp[e + 1], s2 = cp[e + 2], s3 = cp[e + 3];
        const uint4 v0 = *reinterpret_cast<const uint4*>(&h[(size_t)s0 * DIM + co]);
        const uint4 v1 = *reinterpret_cast<const uint4*>(&h[(size_t)s1 * DIM + co]);
        const uint4 v2 = *reinterpret_cast<const uint4*>(&h[(size_t)s2 * DIM + co]);
        const uint4 v3 = *reinterpret_cast<const uint4*>(&h[(size_t)s3 * DIM + co]);
        acc[0] += b2f_lo(v0.x) + b2f_lo(v1.x) + b2f_lo(v2.x) + b2f_lo(v3.x);
        acc[1] += b2f_hi(v0.x) + b2f_hi(v1.x) + b2f_hi(v2.x) + b2f_hi(v3.x);
        acc[2] += b2f_lo(v0.y) + b2f_lo(v1.y) + b2f_lo(v2.y) + b2f_lo(v3.y);
        acc[3] += b2f_hi(v0.y) + b2f_hi(v1.y) + b2f_hi(v2.y) + b2f_hi(v3.y);
        acc[4] += b2f_lo(v0.z) + b2f_lo(v1.z) + b2f_lo(v2.z) + b2f_lo(v3.z);
        acc[5] += b2f_hi(v0.z) + b2f_hi(v1.z) + b2f_hi(v2.z) + b2f_hi(v3.z);
        acc[6] += b2f_lo(v0.w) + b2f_lo(v1.w) + b2f_lo(v2.w) + b2f_lo(v3.w);
        acc[7] += b2f_hi(v0.w) + b2f_hi(v1.w) + b2f_hi(v2.w) + b2f_hi(v3.w);
    }
    for (; e < deg; ++e) {
        const int s = cp[e];
        const uint4 v = *reinterpret_cast<const uint4*>(&h[(size_t)s * DIM + co]);
        acc[0] += b2f_lo(v.x); acc[1] += b2f_hi(v.x);
        acc[2] += b2f_lo(v.y); acc[3] += b2f_hi(v.y);
        acc[4] += b2f_lo(v.z); acc[5] += b2f_hi(v.z);
        acc[6] += b2f_lo(v.w); acc[7] += b2f_hi(v.w);
    }
    const float inv = 1.0f / fmaxf((float)deg, 1.0f);
    uint4 o;
    o.x = (unsigned)f2b(acc[0] * inv) | ((unsigned)f2b(acc[1] * inv) << 16);
    o.y = (unsigned)f2b(acc[2] * inv) | ((unsigned)f2b(acc[3] * inv) << 16);
    o.z = (unsigned)f2b(acc[4] * inv) | ((unsigned)f2b(acc[5] * inv) << 16);
    o.w = (unsigned)f2b(acc[6] * inv) | ((unsigned)f2b(acc[7] * inv) << 16);
    *reinterpret_cast<uint4*>(&aggm[(size_t)node * DIM + co]) = o;
}

// ---- hout = [relu]( aggm @ Wl^T + b + hin @ Wr^T ) via bf16 MFMA, W staged in LDS ----
// 64 nodes/block, 4 waves. Two phases (Wl then Wr); W [128][128] bf16 in LDS padded
// [128][136] (272 B row stride -> ds_read_b128 conflict-free floor).
template <bool RELU>
__global__ __launch_bounds__(256) void xform_mfma_k(const ushort* __restrict__ A0,   // aggm
                                                    const ushort* __restrict__ A1,   // hin (root)
                                                    const ushort* __restrict__ Wl,
                                                    const ushort* __restrict__ Wr,
                                                    const float*  __restrict__ bias,
                                                    ushort* __restrict__ hout) {
    __shared__ ushort Ws[128 * 136];                     // 34816 B
    const int t    = threadIdx.x;
    const int wave = t >> 6;
    const int l    = t & 63;
    const int l16  = l & 15;
    const int lk   = (l >> 4) * 8;                       // k offset within 32-chunk
    const int node = blockIdx.x * 64 + wave * 16 + l16;
    const bool valid = node < N_NODES;

    const int wrow = t >> 1;                             // W staging: row 0..127
    const int wc0  = (t & 1) * 64;                       // 64 ushorts per thread

    f32x4 acc[8];
#pragma unroll
    for (int i = 0; i < 8; ++i) acc[i] = (f32x4){0.f, 0.f, 0.f, 0.f};

    const bf16x8 zfrag = (bf16x8){0, 0, 0, 0, 0, 0, 0, 0};

#pragma unroll
    for (int p = 0; p < 2; ++p) {
        const ushort* Asrc = p ? A1 : A0;
        const ushort* Wsrc = p ? Wr : Wl;

        // issue node-feature loads early (independent of LDS)
        bf16x8 bf[4];
#pragma unroll
        for (int ks = 0; ks < 4; ++ks)
            bf[ks] = valid
                ? *reinterpret_cast<const bf16x8*>(&Asrc[(size_t)node * DIM + ks * 32 + lk])
                : zfrag;

        __syncthreads();                                  // prior-phase LDS reads done
        {   // stage W: 256 threads x 128 B (8 x uint4), coalesced
            const uint4* src = reinterpret_cast<const uint4*>(&Wsrc[(size_t)wrow * DIM + wc0]);
            uint4* dst = reinterpret_cast<uint4*>(&Ws[wrow * 136 + wc0]);
#pragma unroll
            for (int i = 0; i < 8; ++i) dst[i] = src[i];
        }
        __syncthreads();

#pragma unroll
        for (int ks = 0; ks < 4; ++ks) {
            const int kb = ks * 32;
#pragma unroll
            for (int ot = 0; ot < 8; ++ot) {
                const bf16x8 afrag = *reinterpret_cast<const bf16x8*>(
                    &Ws[(ot * 16 + l16) * 136 + kb + lk]);
                acc[ot] = __builtin_amdgcn_mfma_f32_16x16x32_bf16(afrag, bf[ks], acc[ot], 0, 0, 0);
            }
        }
    }

    if (!valid) return;
    const int orow = (l >> 4) * 4;
#pragma unroll
    for (int ot = 0; ot < 8; ++ot) {
        const float4 b4 = *reinterpret_cast<const float4*>(&bias[ot * 16 + orow]);
        float r0 = acc[ot][0] + b4.x;
        float r1 = acc[ot][1] + b4.y;
        float r2 = acc[ot][2] + b4.z;
        float r3 = acc[ot][3] + b4.w;
        if (RELU) {
            r0 = fmaxf(r0, 0.f); r1 = fmaxf(r1, 0.f);
            r2 = fmaxf(r2, 0.f); r3 = fmaxf(r3, 0.f);
        }
        ushort4 s;
        s.x = f2b(r0); s.y = f2b(r1); s.z = f2b(r2); s.w = f2b(r3);
        *reinterpret_cast<ushort4*>(&hout[(size_t)node * DIM + ot * 16 + orow]) = s;
    }
}

// ---- final layer fused: mean-aggregate h2 + 2-dim linear, f32 throughout ----
__global__ __launch_bounds__(256) void out2_fused_k(const ushort* __restrict__ h,
                                                    const unsigned* __restrict__ cnt,
                                                    const int* __restrict__ col,
                                                    const float* __restrict__ Wl,
                                                    const float* __restrict__ Wr,
                                                    const float* __restrict__ bias,
                                                    float* __restrict__ out) {
    __shared__ float wl[256], wr[256];                // [o*128 + k]
    const int t = threadIdx.x;
    wl[t] = Wl[t];
    wr[t] = Wr[t];
    __syncthreads();
    const int g = t >> 4, lane = t & 15;
    const int node = blockIdx.x * 16 + g;
    if (node >= N_NODES) return;
    unsigned deg = cnt[node];
    if (deg > CAP) deg = CAP;
    const int* cp = &col[(size_t)node * CAP];
    const int co = lane * 8;
    float acc[8];
#pragma unroll
    for (int i = 0; i < 8; ++i) acc[i] = 0.f;
    unsigned e = 0;
    for (; e + 4 <= deg; e += 4) {
        const int s0 = cp[e], s1 = cp[e + 1], s2 = cp[e + 2], s3 = cp[e + 3];
        const uint4 v0 = *reinterpret_cast<const uint4*>(&h[(size_t)s0 * DIM + co]);
        const uint4 v1 = *reinterpret_cast<const uint4*>(&h[(size_t)s1 * DIM + co]);
        const uint4 v2 = *reinterpret_cast<const uint4*>(&h[(size_t)s2 * DIM + co]);
        const uint4 v3 = *reinterpret_cast<const uint4*>(&h[(size_t)s3 * DIM + co]);
        acc[0] += b2f_lo(v0.x) + b2f_lo(v1.x) + b2f_lo(v2.x) + b2f_lo(v3.x);
        acc[1] += b2f_hi(v0.x) + b2f_hi(v1.x) + b2f_hi(v2.x) + b2f_hi(v3.x);
        acc[2] += b2f_lo(v0.y) + b2f_lo(v1.y) + b2f_lo(v2.y) + b2f_lo(v3.y);
        acc[3] += b2f_hi(v0.y) + b2f_hi(v1.y) + b2f_hi(v2.y) + b2f_hi(v3.y);
        acc[4] += b2f_lo(v0.z) + b2f_lo(v1.z) + b2f_lo(v2.z) + b2f_lo(v3.z);
        acc[5] += b2f_hi(v0.z) + b2f_hi(v1.z) + b2f_hi(v2.z) + b2f_hi(v3.z);
        acc[6] += b2f_lo(v0.w) + b2f_lo(v1.w) + b2f_lo(v2.w) + b2f_lo(v3.w);
        acc[7] += b2f_hi(v0.w) + b2f_hi(v1.w) + b2f_hi(v2.w) + b2f_hi(v3.w);
    }
    for (; e < deg; ++e) {
        const int s = cp[e];
        const uint4 v = *reinterpret_cast<const uint4*>(&h[(size_t)s * DIM + co]);
        acc[0] += b2f_lo(v.x); acc[1] += b2f_hi(v.x);
        acc[2] += b2f_lo(v.y); acc[3] += b2f_hi(v.y);
        acc[4] += b2f_lo(v.z); acc[5] += b2f_hi(v.z);
        acc[6] += b2f_lo(v.w); acc[7] += b2f_hi(v.w);
    }
    const float inv = 1.0f / fmaxf((float)deg, 1.0f);
    const uint4 rv = *reinterpret_cast<const uint4*>(&h[(size_t)node * DIM + co]);
    float root[8];
    root[0] = b2f_lo(rv.x); root[1] = b2f_hi(rv.x);
    root[2] = b2f_lo(rv.y); root[3] = b2f_hi(rv.y);
    root[4] = b2f_lo(rv.z); root[5] = b2f_hi(rv.z);
    root[6] = b2f_lo(rv.w); root[7] = b2f_hi(rv.w);
    float p0 = 0.f, p1 = 0.f;
#pragma unroll
    for (int j = 0; j < 8; ++j) {
        const float av = acc[j] * inv;
        p0 += av * wl[co + j] + root[j] * wr[co + j];
        p1 += av * wl[128 + co + j] + root[j] * wr[128 + co + j];
    }
#pragma unroll
    for (int m = 1; m < 16; m <<= 1) {
        p0 += __shfl_xor(p0, m);
        p1 += __shfl_xor(p1, m);
    }
    if (lane == 0) {
        out[(size_t)node * 2 + 0] = p0 + bias[0];
        out[(size_t)node * 2 + 1] = p1 + bias[1];
    }
}

extern "C" void kernel_launch(void* const* d_in, const int* in_sizes, int n_in,
                              void* d_out, int out_size, void* d_ws, size_t ws_size,
                              hipStream_t stream) {
    const float* x   = (const float*)d_in[0];
    const int*   ei  = (const int*)d_in[1];
    const float* Wl0 = (const float*)d_in[2];
    const float* Wr0 = (const float*)d_in[3];
    const float* b0  = (const float*)d_in[4];
    const float* Wl1 = (const float*)d_in[5];
    const float* Wr1 = (const float*)d_in[6];
    const float* b1  = (const float*)d_in[7];
    const float* Wl2 = (const float*)d_in[8];
    const float* Wr2 = (const float*)d_in[9];
    const float* b2  = (const float*)d_in[10];

    char* ws = (char*)d_ws;
    unsigned* flag = (unsigned*)(ws + OFF_FLAG);
    unsigned* cnt  = (unsigned*)(ws + OFF_CNT);
    int*      col  = (int*)(ws + OFF_COL);
    ushort*   xbf  = (ushort*)(ws + OFF_XBF);
    ushort*   aggm = (ushort*)(ws + OFF_AGG);
    ushort*   h1   = (ushort*)(ws + OFF_H1);
    ushort*   h2   = (ushort*)(ws + OFF_H2);
    ushort*   wl0b = (ushort*)(ws + OFF_WL0);
    ushort*   wr0b = (ushort*)(ws + OFF_WR0);
    ushort*   wl1b = (ushort*)(ws + OFF_WL1);
    ushort*   wr1b = (ushort*)(ws + OFF_WR1);
    float*    out  = (float*)d_out;

    prep_k<<<6250 + 64, 256, 0, stream>>>(ei, x, Wl0, Wr0, Wl1, Wr1,
                                          flag, cnt, xbf, wl0b, wr0b, wl1b, wr1b);
    fillcsr_k<<<(N_EDGES / 4 + 255) / 256, 256, 0, stream>>>(ei, flag, cnt, col);

    // layer 0: xbf -> h1
    agg_k<<<(N_NODES + 15) / 16, 256, 0, stream>>>(xbf, cnt, col, aggm);
    xform_mfma_k<true><<<(N_NODES + 63) / 64, 256, 0, stream>>>(aggm, xbf, wl0b, wr0b, b0, h1);
    // layer 1: h1 -> h2
    agg_k<<<(N_NODES + 15) / 16, 256, 0, stream>>>(h1, cnt, col, aggm);
    xform_mfma_k<true><<<(N_NODES + 63) / 64, 256, 0, stream>>>(aggm, h1, wl1b, wr1b, b1, h2);
    // layer 2 fused: aggregate h2 + linear -> out
    out2_fused_k<<<(N_NODES + 15) / 16, 256, 0, stream>>>(h2, cnt, col, Wl2, Wr2, b2, out);
}

// Round 7
// 133.674 us; speedup vs baseline: 2.0127x; 1.1433x over previous
//
#include <hip/hip_runtime.h>
#include <hip/hip_bf16.h>

#define N_NODES 50000
#define N_EDGES 600000
#define DIM 128
#define CAP 64          // bucket capacity; deg ~ Poisson(12), max over 50K nodes ~ 38, guarded anyway

typedef short bf16x8 __attribute__((ext_vector_type(8)));
typedef float f32x4 __attribute__((ext_vector_type(4)));

__device__ __forceinline__ ushort f2b(float f) {
    __hip_bfloat16 h = __float2bfloat16(f);
    return *reinterpret_cast<ushort*>(&h);
}
__device__ __forceinline__ float b2f_lo(unsigned u) { return __uint_as_float(u << 16); }
__device__ __forceinline__ float b2f_hi(unsigned u) { return __uint_as_float(u & 0xffff0000u); }

static constexpr size_t alignup(size_t x) { return (x + 255) & ~size_t(255); }
static constexpr size_t OFF_FLAG = 0;
static constexpr size_t OFF_CNT  = 256;
static constexpr size_t OFF_COL  = alignup(OFF_CNT + sizeof(unsigned) * N_NODES);
static constexpr size_t OFF_XBF  = alignup(OFF_COL + sizeof(int) * (size_t)N_NODES * CAP);
static constexpr size_t OFF_AGG  = alignup(OFF_XBF + sizeof(ushort) * N_NODES * DIM);
static constexpr size_t OFF_H1   = alignup(OFF_AGG + sizeof(ushort) * N_NODES * DIM);
static constexpr size_t OFF_Z    = alignup(OFF_H1 + sizeof(ushort) * N_NODES * DIM);
static constexpr size_t OFF_RT   = alignup(OFF_Z + sizeof(float) * 2 * N_NODES);
static constexpr size_t OFF_WL0  = alignup(OFF_RT + sizeof(float) * 2 * N_NODES);
static constexpr size_t OFF_WR0  = alignup(OFF_WL0 + sizeof(ushort) * DIM * DIM);
static constexpr size_t OFF_WL1  = alignup(OFF_WR0 + sizeof(ushort) * DIM * DIM);
static constexpr size_t OFF_WR1  = alignup(OFF_WL1 + sizeof(ushort) * DIM * DIM);

// ---- prep: zero cnt + detect edge dtype + x->bf16 + 4x W->bf16, one dispatch ----
__global__ __launch_bounds__(256) void prep_k(const int* __restrict__ ei,
                                              const float* __restrict__ x,
                                              const float* __restrict__ wa, const float* __restrict__ wb,
                                              const float* __restrict__ wc, const float* __restrict__ wd,
                                              unsigned* __restrict__ flag,
                                              unsigned* __restrict__ cnt,
                                              ushort* __restrict__ xbf,
                                              ushort* __restrict__ oa, ushort* __restrict__ ob,
                                              ushort* __restrict__ oc, ushort* __restrict__ od) {
    const int bid = blockIdx.x, t = threadIdx.x;
    if (bid < 6250) {
        const int i = bid * 256 + t;                 // f2b: 4 floats/thread
        float4 v = reinterpret_cast<const float4*>(x)[i];
        ushort4 o;
        o.x = f2b(v.x); o.y = f2b(v.y); o.z = f2b(v.z); o.w = f2b(v.w);
        reinterpret_cast<ushort4*>(xbf)[i] = o;
        if (i < N_NODES) cnt[i] = 0u;
        if (bid == 0) {
            __shared__ unsigned any;
            if (t == 0) any = 0u;
            __syncthreads();
            unsigned hv = 0;
#pragma unroll
            for (int j = 0; j < 4; ++j) hv |= (unsigned)ei[2 * (t * 4 + j) + 1];
            if (hv) atomicOr(&any, 1u);
            __syncthreads();
            if (t == 0) *flag = any;                 // !=0 -> int32 layout, ==0 -> int64
        }
    } else {
        const int wb_i = bid - 6250;                 // 64 blocks: 4 mats x 16 blocks
        const int w = wb_i >> 4;
        const float* src = (w == 0) ? wa : (w == 1) ? wb : (w == 2) ? wc : wd;
        ushort* dst      = (w == 0) ? oa : (w == 1) ? ob : (w == 2) ? oc : od;
        const int i = (wb_i & 15) * 256 + t;         // 4096 float4 units per matrix
        float4 v = reinterpret_cast<const float4*>(src)[i];
        ushort4 o;
        o.x = f2b(v.x); o.y = f2b(v.y); o.z = f2b(v.z); o.w = f2b(v.w);
        reinterpret_cast<ushort4*>(dst)[i] = o;
    }
}

// ---- bucketed CSR fill: col[dst*CAP + pos], cnt[dst] ends as degree. 4 edges/thread ----
__global__ void fillcsr_k(const int* __restrict__ ei, const unsigned* __restrict__ flag,
                          unsigned* __restrict__ cnt, int* __restrict__ col) {
    int e0 = (blockIdx.x * 256 + threadIdx.x) * 4;
    if (e0 >= N_EDGES) return;
    int s[4], d[4];
    if (*flag) {
        uint4 sv = *reinterpret_cast<const uint4*>(&ei[e0]);
        uint4 dv = *reinterpret_cast<const uint4*>(&ei[N_EDGES + e0]);
        s[0] = sv.x; s[1] = sv.y; s[2] = sv.z; s[3] = sv.w;
        d[0] = dv.x; d[1] = dv.y; d[2] = dv.z; d[3] = dv.w;
    } else {
        uint4 sa = *reinterpret_cast<const uint4*>(&ei[2 * e0]);
        uint4 sb = *reinterpret_cast<const uint4*>(&ei[2 * e0 + 4]);
        uint4 da = *reinterpret_cast<const uint4*>(&ei[2 * (N_EDGES + e0)]);
        uint4 db = *reinterpret_cast<const uint4*>(&ei[2 * (N_EDGES + e0) + 4]);
        s[0] = sa.x; s[1] = sa.z; s[2] = sb.x; s[3] = sb.z;
        d[0] = da.x; d[1] = da.z; d[2] = db.x; d[3] = db.z;
    }
#pragma unroll
    for (int i = 0; i < 4; ++i) {
        unsigned pos = atomicAdd(&cnt[d[i]], 1u);
        if (pos < CAP) col[(size_t)d[i] * CAP + pos] = s[i];
    }
}

// ---- mean-aggregate (bf16 in, f32 accum, bf16 out): 16 nodes/block, 16 lanes/node ----
__global__ __launch_bounds__(256) void agg_k(const ushort* __restrict__ h,
                                             const unsigned* __restrict__ cnt,
                                             const int* __restrict__ col,
                                             ushort* __restrict__ aggm) {
    const int g = threadIdx.x >> 4, lane = threadIdx.x & 15;
    const int node = blockIdx.x * 16 + g;
    if (node >= N_NODES) return;
    unsigned deg = cnt[node];
    if (deg > CAP) deg = CAP;
    const int* cp = &col[(size_t)node * CAP];
    float acc[8];
#pragma unroll
    for (int i = 0; i < 8; ++i) acc[i] = 0.f;
    const int co = lane * 8;
    unsigned e = 0;
    for (; e + 4 <= deg; e += 4) {
        const int s0 = cp[e], s1 = cp[e + 1], s2 = cp[e + 2], s3 = cp[e + 3];
        const uint4 v0 = *reinterpret_cast<const uint4*>(&h[(size_t)s0 * DIM + co]);
        const uint4 v1 = *reinterpret_cast<const uint4*>(&h[(size_t)s1 * DIM + co]);
        const uint4 v2 = *reinterpret_cast<const uint4*>(&h[(size_t)s2 * DIM + co]);
        const uint4 v3 = *reinterpret_cast<const uint4*>(&h[(size_t)s3 * DIM + co]);
        acc[0] += b2f_lo(v0.x) + b2f_lo(v1.x) + b2f_lo(v2.x) + b2f_lo(v3.x);
        acc[1] += b2f_hi(v0.x) + b2f_hi(v1.x) + b2f_hi(v2.x) + b2f_hi(v3.x);
        acc[2] += b2f_lo(v0.y) + b2f_lo(v1.y) + b2f_lo(v2.y) + b2f_lo(v3.y);
        acc[3] += b2f_hi(v0.y) + b2f_hi(v1.y) + b2f_hi(v2.y) + b2f_hi(v3.y);
        acc[4] += b2f_lo(v0.z) + b2f_lo(v1.z) + b2f_lo(v2.z) + b2f_lo(v3.z);
        acc[5] += b2f_hi(v0.z) + b2f_hi(v1.z) + b2f_hi(v2.z) + b2f_hi(v3.z);
        acc[6] += b2f_lo(v0.w) + b2f_lo(v1.w) + b2f_lo(v2.w) + b2f_lo(v3.w);
        acc[7] += b2f_hi(v0.w) + b2f_hi(v1.w) + b2f_hi(v2.w) + b2f_hi(v3.w);
    }
    for (; e < deg; ++e) {
        const int s = cp[e];
        const uint4 v = *reinterpret_cast<const uint4*>(&h[(size_t)s * DIM + co]);
        acc[0] += b2f_lo(v.x); acc[1] += b2f_hi(v.x);
        acc[2] += b2f_lo(v.y); acc[3] += b2f_hi(v.y);
        acc[4] += b2f_lo(v.z); acc[5] += b2f_hi(v.z);
        acc[6] += b2f_lo(v.w); acc[7] += b2f_hi(v.w);
    }
    const float inv = 1.0f / fmaxf((float)deg, 1.0f);
    uint4 o;
    o.x = (unsigned)f2b(acc[0] * inv) | ((unsigned)f2b(acc[1] * inv) << 16);
    o.y = (unsigned)f2b(acc[2] * inv) | ((unsigned)f2b(acc[3] * inv) << 16);
    o.z = (unsigned)f2b(acc[4] * inv) | ((unsigned)f2b(acc[5] * inv) << 16);
    o.w = (unsigned)f2b(acc[6] * inv) | ((unsigned)f2b(acc[7] * inv) << 16);
    *reinterpret_cast<uint4*>(&aggm[(size_t)node * DIM + co]) = o;
}

// ---- hout = relu( aggm @ Wl^T + b + hin @ Wr^T ) via bf16 MFMA, W staged in LDS ----
__global__ __launch_bounds__(256) void xform_mfma_k(const ushort* __restrict__ A0,   // aggm
                                                    const ushort* __restrict__ A1,   // hin (root)
                                                    const ushort* __restrict__ Wl,
                                                    const ushort* __restrict__ Wr,
                                                    const float*  __restrict__ bias,
                                                    ushort* __restrict__ hout) {
    __shared__ ushort Ws[128 * 136];                     // 34816 B
    const int t    = threadIdx.x;
    const int wave = t >> 6;
    const int l    = t & 63;
    const int l16  = l & 15;
    const int lk   = (l >> 4) * 8;                       // k offset within 32-chunk
    const int node = blockIdx.x * 64 + wave * 16 + l16;
    const bool valid = node < N_NODES;

    const int wrow = t >> 1;                             // W staging: row 0..127
    const int wc0  = (t & 1) * 64;                       // 64 ushorts per thread

    f32x4 acc[8];
#pragma unroll
    for (int i = 0; i < 8; ++i) acc[i] = (f32x4){0.f, 0.f, 0.f, 0.f};

    const bf16x8 zfrag = (bf16x8){0, 0, 0, 0, 0, 0, 0, 0};

#pragma unroll
    for (int p = 0; p < 2; ++p) {
        const ushort* Asrc = p ? A1 : A0;
        const ushort* Wsrc = p ? Wr : Wl;

        bf16x8 bf[4];
#pragma unroll
        for (int ks = 0; ks < 4; ++ks)
            bf[ks] = valid
                ? *reinterpret_cast<const bf16x8*>(&Asrc[(size_t)node * DIM + ks * 32 + lk])
                : zfrag;

        __syncthreads();
        {   // stage W: 256 threads x 128 B (8 x uint4), coalesced
            const uint4* src = reinterpret_cast<const uint4*>(&Wsrc[(size_t)wrow * DIM + wc0]);
            uint4* dst = reinterpret_cast<uint4*>(&Ws[wrow * 136 + wc0]);
#pragma unroll
            for (int i = 0; i < 8; ++i) dst[i] = src[i];
        }
        __syncthreads();

#pragma unroll
        for (int ks = 0; ks < 4; ++ks) {
            const int kb = ks * 32;
#pragma unroll
            for (int ot = 0; ot < 8; ++ot) {
                const bf16x8 afrag = *reinterpret_cast<const bf16x8*>(
                    &Ws[(ot * 16 + l16) * 136 + kb + lk]);
                acc[ot] = __builtin_amdgcn_mfma_f32_16x16x32_bf16(afrag, bf[ks], acc[ot], 0, 0, 0);
            }
        }
    }

    if (!valid) return;
    const int orow = (l >> 4) * 4;
#pragma unroll
    for (int ot = 0; ot < 8; ++ot) {
        const float4 b4 = *reinterpret_cast<const float4*>(&bias[ot * 16 + orow]);
        float r0 = fmaxf(acc[ot][0] + b4.x, 0.f);
        float r1 = fmaxf(acc[ot][1] + b4.y, 0.f);
        float r2 = fmaxf(acc[ot][2] + b4.z, 0.f);
        float r3 = fmaxf(acc[ot][3] + b4.w, 0.f);
        ushort4 s;
        s.x = f2b(r0); s.y = f2b(r1); s.z = f2b(r2); s.w = f2b(r3);
        *reinterpret_cast<ushort4*>(&hout[(size_t)node * DIM + ot * 16 + orow]) = s;
    }
}

// ---- final transform: h2 = relu(aggm@Wl1^T + b1 + h1@Wr1^T) computed in regs, never stored.
// Epilogue projects to layer-2: z[n] = h2[n] @ Wl2^T (2-dim), rt[n] = h2[n] @ Wr2^T + b2.
// (mean-agg commutes with the linear map: agg(h2)@Wl2^T = agg(z))
__global__ __launch_bounds__(256) void xform_final_k(const ushort* __restrict__ A0,   // aggm
                                                     const ushort* __restrict__ A1,   // h1 (root)
                                                     const ushort* __restrict__ Wl,
                                                     const ushort* __restrict__ Wr,
                                                     const float*  __restrict__ bias, // b1
                                                     const float*  __restrict__ Wl2,
                                                     const float*  __restrict__ Wr2,
                                                     const float*  __restrict__ b2,
                                                     float* __restrict__ z,
                                                     float* __restrict__ rt) {
    __shared__ ushort Ws[128 * 136];
    __shared__ float wl2s[256], wr2s[256];               // [o2*128 + k]
    const int t    = threadIdx.x;
    const int wave = t >> 6;
    const int l    = t & 63;
    const int l16  = l & 15;
    const int lk   = (l >> 4) * 8;
    const int node = blockIdx.x * 64 + wave * 16 + l16;
    const bool valid = node < N_NODES;

    const int wrow = t >> 1;
    const int wc0  = (t & 1) * 64;

    wl2s[t] = Wl2[t];
    wr2s[t] = Wr2[t];

    f32x4 acc[8];
#pragma unroll
    for (int i = 0; i < 8; ++i) acc[i] = (f32x4){0.f, 0.f, 0.f, 0.f};

    const bf16x8 zfrag = (bf16x8){0, 0, 0, 0, 0, 0, 0, 0};

#pragma unroll
    for (int p = 0; p < 2; ++p) {
        const ushort* Asrc = p ? A1 : A0;
        const ushort* Wsrc = p ? Wr : Wl;

        bf16x8 bf[4];
#pragma unroll
        for (int ks = 0; ks < 4; ++ks)
            bf[ks] = valid
                ? *reinterpret_cast<const bf16x8*>(&Asrc[(size_t)node * DIM + ks * 32 + lk])
                : zfrag;

        __syncthreads();
        {
            const uint4* src = reinterpret_cast<const uint4*>(&Wsrc[(size_t)wrow * DIM + wc0]);
            uint4* dst = reinterpret_cast<uint4*>(&Ws[wrow * 136 + wc0]);
#pragma unroll
            for (int i = 0; i < 8; ++i) dst[i] = src[i];
        }
        __syncthreads();

#pragma unroll
        for (int ks = 0; ks < 4; ++ks) {
            const int kb = ks * 32;
#pragma unroll
            for (int ot = 0; ot < 8; ++ot) {
                const bf16x8 afrag = *reinterpret_cast<const bf16x8*>(
                    &Ws[(ot * 16 + l16) * 136 + kb + lk]);
                acc[ot] = __builtin_amdgcn_mfma_f32_16x16x32_bf16(afrag, bf[ks], acc[ot], 0, 0, 0);
            }
        }
    }

    // epilogue: relu(h2) in regs -> project onto Wl2/Wr2 (per-lane partial over 32 o's)
    const int orow = (l >> 4) * 4;
    float z0 = 0.f, z1 = 0.f, r0s = 0.f, r1s = 0.f;
#pragma unroll
    for (int ot = 0; ot < 8; ++ot) {
        const int o = ot * 16 + orow;
        const float4 b4 = *reinterpret_cast<const float4*>(&bias[o]);
        const float h0 = fmaxf(acc[ot][0] + b4.x, 0.f);
        const float h1v = fmaxf(acc[ot][1] + b4.y, 0.f);
        const float h2v = fmaxf(acc[ot][2] + b4.z, 0.f);
        const float h3 = fmaxf(acc[ot][3] + b4.w, 0.f);
        z0  += h0 * wl2s[o] + h1v * wl2s[o + 1] + h2v * wl2s[o + 2] + h3 * wl2s[o + 3];
        z1  += h0 * wl2s[128 + o] + h1v * wl2s[128 + o + 1] + h2v * wl2s[128 + o + 2] + h3 * wl2s[128 + o + 3];
        r0s += h0 * wr2s[o] + h1v * wr2s[o + 1] + h2v * wr2s[o + 2] + h3 * wr2s[o + 3];
        r1s += h0 * wr2s[128 + o] + h1v * wr2s[128 + o + 1] + h2v * wr2s[128 + o + 2] + h3 * wr2s[128 + o + 3];
    }
    // combine the 4 lanes (xor 16, 32) holding the same node
    z0  += __shfl_xor(z0, 16);  z0  += __shfl_xor(z0, 32);
    z1  += __shfl_xor(z1, 16);  z1  += __shfl_xor(z1, 32);
    r0s += __shfl_xor(r0s, 16); r0s += __shfl_xor(r0s, 32);
    r1s += __shfl_xor(r1s, 16); r1s += __shfl_xor(r1s, 32);
    if ((l >> 4) == 0 && valid) {
        float2 zv = {z0, z1};
        float2 rv = {r0s + b2[0], r1s + b2[1]};
        *reinterpret_cast<float2*>(&z[(size_t)node * 2])  = zv;
        *reinterpret_cast<float2*>(&rt[(size_t)node * 2]) = rv;
    }
}

// ---- out[n] = mean_{s in N(n)} z[s] + rt[n]; 8 lanes/node ----
__global__ __launch_bounds__(256) void outgather_k(const float* __restrict__ z,
                                                   const float* __restrict__ rt,
                                                   const unsigned* __restrict__ cnt,
                                                   const int* __restrict__ col,
                                                   float* __restrict__ out) {
    const int g = threadIdx.x >> 3, lane = threadIdx.x & 7;
    const int node = blockIdx.x * 32 + g;
    if (node >= N_NODES) return;
    unsigned deg = cnt[node];
    if (deg > CAP) deg = CAP;
    const int* cp = &col[(size_t)node * CAP];
    float s0 = 0.f, s1 = 0.f;
    for (unsigned e = lane; e < deg; e += 8) {
        const int s = cp[e];
        const float2 v = *reinterpret_cast<const float2*>(&z[(size_t)s * 2]);
        s0 += v.x; s1 += v.y;
    }
#pragma unroll
    for (int m = 1; m < 8; m <<= 1) {
        s0 += __shfl_xor(s0, m);
        s1 += __shfl_xor(s1, m);
    }
    if (lane == 0) {
        const float inv = 1.0f / fmaxf((float)deg, 1.0f);
        const float2 rv = *reinterpret_cast<const float2*>(&rt[(size_t)node * 2]);
        float2 o = {s0 * inv + rv.x, s1 * inv + rv.y};
        *reinterpret_cast<float2*>(&out[(size_t)node * 2]) = o;
    }
}

extern "C" void kernel_launch(void* const* d_in, const int* in_sizes, int n_in,
                              void* d_out, int out_size, void* d_ws, size_t ws_size,
                              hipStream_t stream) {
    const float* x   = (const float*)d_in[0];
    const int*   ei  = (const int*)d_in[1];
    const float* Wl0 = (const float*)d_in[2];
    const float* Wr0 = (const float*)d_in[3];
    const float* b0  = (const float*)d_in[4];
    const float* Wl1 = (const float*)d_in[5];
    const float* Wr1 = (const float*)d_in[6];
    const float* b1  = (const float*)d_in[7];
    const float* Wl2 = (const float*)d_in[8];
    const float* Wr2 = (const float*)d_in[9];
    const float* b2  = (const float*)d_in[10];

    char* ws = (char*)d_ws;
    unsigned* flag = (unsigned*)(ws + OFF_FLAG);
    unsigned* cnt  = (unsigned*)(ws + OFF_CNT);
    int*      col  = (int*)(ws + OFF_COL);
    ushort*   xbf  = (ushort*)(ws + OFF_XBF);
    ushort*   aggm = (ushort*)(ws + OFF_AGG);
    ushort*   h1   = (ushort*)(ws + OFF_H1);
    float*    zbuf = (float*)(ws + OFF_Z);
    float*    rtb  = (float*)(ws + OFF_RT);
    ushort*   wl0b = (ushort*)(ws + OFF_WL0);
    ushort*   wr0b = (ushort*)(ws + OFF_WR0);
    ushort*   wl1b = (ushort*)(ws + OFF_WL1);
    ushort*   wr1b = (ushort*)(ws + OFF_WR1);
    float*    out  = (float*)d_out;

    prep_k<<<6250 + 64, 256, 0, stream>>>(ei, x, Wl0, Wr0, Wl1, Wr1,
                                          flag, cnt, xbf, wl0b, wr0b, wl1b, wr1b);
    fillcsr_k<<<(N_EDGES / 4 + 255) / 256, 256, 0, stream>>>(ei, flag, cnt, col);

    // layer 0: xbf -> h1
    agg_k<<<(N_NODES + 15) / 16, 256, 0, stream>>>(xbf, cnt, col, aggm);
    xform_mfma_k<<<(N_NODES + 63) / 64, 256, 0, stream>>>(aggm, xbf, wl0b, wr0b, b0, h1);
    // layer 1 + layer-2 projection: h1 -> z, rt (h2 never materialized)
    agg_k<<<(N_NODES + 15) / 16, 256, 0, stream>>>(h1, cnt, col, aggm);
    xform_final_k<<<(N_NODES + 63) / 64, 256, 0, stream>>>(aggm, h1, wl1b, wr1b, b1,
                                                           Wl2, Wr2, b2, zbuf, rtb);
    // layer 2: out = mean-gather(z) + rt
    outgather_k<<<(N_NODES + 31) / 32, 256, 0, stream>>>(zbuf, rtb, cnt, col, out);
}